// Round 8
// baseline (306.475 us; speedup 1.0000x reference)
//
#include <hip/hip_runtime.h>
#include <hip/hip_bf16.h>

// Problem constants
#define M_ROWS  32768   // B*H*W
#define D_DIM   512     // C == latent dim
#define K_CODES 1024
#define HW      1024
#define IMG_STRIDE (D_DIM * HW)   // 524288

// d_out scratch: zh swizzled bf16 (32 MB) lives in the out_q region until
// vq_final/vq_recheckB overwrite it (zh is dead after vq_score).
// ws layout (bytes):
#define WH_OFF   0u          // 1 MB   swizzled cb-hi bf16
#define A_OFF    1048576u    // 128 KB A[i] (numpy-pairwise)
#define W_OFF    1179648u    // 4 KB   W[n]
#define PART_OFF 1312768u    // 2.62 MB per-(row,bn) top3 partials
#define WL2_OFF  4065280u    // 128 KB worklist flag==2
#define CNT_OFF  4196352u    // 8 B    counters

// 1-term bf16 error: pairwise sigma ~4.3e-5 -> 7.5 sigma = 3.2e-4, plus fp32
// reorder/grid window 1.22e-4 -> 4.4e-4; pad to 5e-4.
#define WINDOW 5.0e-4f

// ---- exact RNE fp32 ops the compiler can't contract/reassociate ----
__device__ __forceinline__ float fmul32(float a, float b) {
  float r; asm volatile("v_mul_f32 %0, %1, %2" : "=v"(r) : "v"(a), "v"(b)); return r;
}
__device__ __forceinline__ float fadd32(float a, float b) {
  float r; asm volatile("v_add_f32 %0, %1, %2" : "=v"(r) : "v"(a), "v"(b)); return r;
}
__device__ __forceinline__ float pair8(const float* r) {
  return fadd32(fadd32(fadd32(r[0], r[1]), fadd32(r[2], r[3])),
                fadd32(fadd32(r[4], r[5]), fadd32(r[6], r[7])));
}

__device__ __forceinline__ unsigned short f2bf(float x) {
  __hip_bfloat16 h = __float2bfloat16(x);
  unsigned short u; __builtin_memcpy(&u, &h, 2); return u;
}

typedef __attribute__((ext_vector_type(8))) short b8;
typedef __attribute__((ext_vector_type(4))) float f4;

// top-3 tracking (values s1<=s2<=s3; indices for first two; first-index ties)
struct T3 { float s1, s2, s3; int n1, n2; };
__device__ __forceinline__ void t3_merge(T3& a, const T3& bb) {
  T3 x = a, y = bb;
  bool bf = (y.s1 < x.s1) || (y.s1 == x.s1 && y.n1 < x.n1);
  if (bf) { T3 t = x; x = y; y = t; }
  float rs2; int rn2; float rs3;
  bool c2 = (y.s1 < x.s2) || (y.s1 == x.s2 && y.n1 < x.n2);
  if (c2) { rs2 = y.s1; rn2 = y.n1; rs3 = fminf(x.s2, y.s2); }
  else    { rs2 = x.s2; rn2 = x.n2; rs3 = fminf(x.s3, y.s1); }
  a.s1 = x.s1; a.n1 = x.n1; a.s2 = rs2; a.n2 = rn2; a.s3 = rs3;
}

// ---------------------------------------------------------------------------
// R7: prep re-parallelized. Old geometry tied each wave to 64 pos x ALL 512
// channels -> only 512 waves chip-wide (0.5 wave/SIMD) on a 96 MB stream.
// New: 512 blocks x 4 waves; the 4 waves of a block share 64 pos and split
// the channels 128 each (exactly the old blk[w] range). Per-wave private LDS
// staging; one final barrier; lanes 0-63 combine A = (b0+b1)+(b2+b3) in the
// exact original fp32 order. 2048 waves -> 8 waves/CU. Bodies byte-identical.
// prepw rides along as blocks 512..515 (original 256-thread body).
__global__ __launch_bounds__(256) void vq_prep(const float* __restrict__ z,
                                               float* __restrict__ A,
                                               char* __restrict__ zh_b,
                                               const float* __restrict__ cb,
                                               float* __restrict__ W,
                                               char* __restrict__ wh_b,
                                               int* __restrict__ cnt) {
  __shared__ float zs[4][64 * 68];
  __shared__ float bsum[4][64];
  if (blockIdx.x >= 512) {      // ---- prepw part (4 blocks x 256 threads) ----
    if (blockIdx.x == 512 && threadIdx.x < 2) cnt[threadIdx.x] = 0;
    const int n = (blockIdx.x - 512) * 256 + threadIdx.x;
    const float* wp = cb + (size_t)n * D_DIM;
    const size_t nbase = (size_t)(n >> 4) * 1024 + (size_t)(n & 15) * 16;
    float r8w[8], blkw[4];
    alignas(16) unsigned short hsw[8];
#pragma unroll
    for (int bb = 0; bb < 4; ++bb) {
#pragma unroll
      for (int g = 0; g < 16; ++g) {
        float vv[8];
#pragma unroll
        for (int k = 0; k < 8; ++k) vv[k] = wp[bb * 128 + g * 8 + k];
#pragma unroll
        for (int k = 0; k < 8; ++k) {
          float pq = fmul32(vv[k], vv[k]);
          if (g == 0) r8w[k] = pq;
          else        r8w[k] = fadd32(r8w[k], pq);
          hsw[k] = f2bf(vv[k]);
        }
        const int kc = bb * 4 + (g >> 2), q = g & 3;
        *(uint4*)(wh_b + (size_t)kc * 65536 + q * 256 + nbase) = *(uint4*)hsw;
      }
      blkw[bb] = pair8(r8w);
    }
    W[n] = fadd32(fadd32(blkw[0], blkw[1]), fadd32(blkw[2], blkw[3]));
    return;
  }
  // ---- prep part (512 blocks x 256 threads; wave w = channels 128w..) ----
  const int w = threadIdx.x >> 6, t = threadIdx.x & 63;
  const int i0 = blockIdx.x * 64;
  const int b = i0 >> 10, hw0 = i0 & 1023;
  const float* zbase = z + (size_t)b * IMG_STRIDE + hw0;
  float* zsw = zs[w];
  const int pos = i0 + t;
  const size_t mbase = (size_t)(pos >> 4) * 1024 + (size_t)(pos & 15) * 16;
  float r8[8];
  float blkw = 0.f;
  alignas(16) unsigned short hs[8];
#pragma unroll
  for (int g = 0; g < 2; ++g) {
    const int cg = w * 2 + g;           // 64-channel group index
    __syncthreads();
    {
      const int l = t & 15, j0 = t >> 4;
#pragma unroll
      for (int jj = 0; jj < 16; ++jj) {
        int j = j0 * 16 + jj;
        float4 vv = *(const float4*)(zbase + (size_t)(cg * 64 + j) * HW + 4 * l);
        *(float4*)(zsw + j * 68 + 4 * l) = vv;
      }
    }
    __syncthreads();
#pragma unroll
    for (int j = 0; j < 64; ++j) {
      const int c = cg * 64 + j;
      float v = zsw[j * 68 + t];
      hs[j & 7] = f2bf(v);
      if ((j & 7) == 7) {
        const int kc = c >> 5, q = (c >> 3) & 3;
        *(uint4*)(zh_b + (size_t)kc * 2097152 + q * 256 + mbase) = *(uint4*)hs;
      }
      float pq = fmul32(v, v);
      const int k = c & 7, m = c & 127;
      if (m < 8) r8[k] = pq;
      else       r8[k] = fadd32(r8[k], pq);
      if (m == 127) blkw = pair8(r8);
    }
  }
  bsum[w][t] = blkw;
  __syncthreads();
  if (threadIdx.x < 64)
    A[i0 + threadIdx.x] = fadd32(fadd32(bsum[0][threadIdx.x], bsum[1][threadIdx.x]),
                                 fadd32(bsum[2][threadIdx.x], bsum[3][threadIdx.x]));
}

// ---------------------------------------------------------------------------
// 1-term MFMA scoring (R3 version, verified 80.6 µs — untouched).
__global__ __launch_bounds__(256, 2) void vq_score(
    const char* __restrict__ zh_b, const char* __restrict__ wh_b,
    const float* __restrict__ Wws, float* __restrict__ part)
{
  __shared__ float red[1280];   // [128 rows][2 wc][5] epilogue reduce
  const int tid = threadIdx.x;
  const int lane = tid & 63, wave = tid >> 6;
  const int wr = wave >> 1, wc = wave & 1;
  const int bm = blockIdx.x & 255, bn = blockIdx.x >> 8;
  const int m0 = bm * 128, n0 = bn * 256;

  f4 acc[4][8];
#pragma unroll
  for (int r = 0; r < 4; ++r)
#pragma unroll
    for (int v = 0; v < 8; ++v) acc[r][v] = (f4)(0.0f);

  const char* gA_w = zh_b + (size_t)bm * 8192 + (size_t)(wr * 4) * 1024 + (size_t)lane * 16;
  const char* gB_w = wh_b + (size_t)bn * 16384 + (size_t)(wc * 8) * 1024 + (size_t)lane * 16;

  b8 ar[2][4], br[2][8];
#pragma unroll
  for (int r = 0; r < 4; ++r)
    ar[0][r] = *(const b8*)(gA_w + (size_t)r * 1024);
#pragma unroll
  for (int v = 0; v < 8; ++v)
    br[0][v] = *(const b8*)(gB_w + (size_t)v * 1024);

#pragma unroll
  for (int kc = 0; kc < 16; ++kc) {
    const int cur = kc & 1, nxt = cur ^ 1;
    if (kc + 1 < 16) {
      const char* gA = gA_w + (size_t)(kc + 1) * 2097152;
      const char* gB = gB_w + (size_t)(kc + 1) * 65536;
#pragma unroll
      for (int r = 0; r < 4; ++r) ar[nxt][r] = *(const b8*)(gA + (size_t)r * 1024);
#pragma unroll
      for (int v = 0; v < 8; ++v) br[nxt][v] = *(const b8*)(gB + (size_t)v * 1024);
    }
#pragma unroll
    for (int r = 0; r < 4; ++r) {
#pragma unroll
      for (int v = 0; v < 8; ++v)
        acc[r][v] = __builtin_amdgcn_mfma_f32_16x16x32_bf16(ar[cur][r], br[cur][v],
                                                            acc[r][v], 0, 0, 0);
    }
  }

  const int l15 = lane & 15, quad = lane >> 4;
  float sW[8];
#pragma unroll
  for (int v = 0; v < 8; ++v) sW[v] = Wws[n0 + wc * 128 + v * 16 + l15];

#pragma unroll
  for (int r = 0; r < 4; ++r) {
#pragma unroll
    for (int reg = 0; reg < 4; ++reg) {
      T3 t; t.s1 = t.s2 = t.s3 = 3.4e38f; t.n1 = 0; t.n2 = 0;
#pragma unroll
      for (int v = 0; v < 8; ++v) {
        float s = fmaf(-2.f, acc[r][v][reg], sW[v]);
        int n = n0 + wc * 128 + v * 16 + l15;
        if (s < t.s1)      { t.s3 = t.s2; t.s2 = t.s1; t.n2 = t.n1; t.s1 = s; t.n1 = n; }
        else if (s < t.s2) { t.s3 = t.s2; t.s2 = s; t.n2 = n; }
        else if (s < t.s3) { t.s3 = s; }
      }
#pragma unroll
      for (int m = 1; m <= 8; m <<= 1) {   // butterfly within 16-lane quad
        T3 o;
        o.s1 = __shfl_xor(t.s1, m); o.s2 = __shfl_xor(t.s2, m); o.s3 = __shfl_xor(t.s3, m);
        o.n1 = __shfl_xor(t.n1, m); o.n2 = __shfl_xor(t.n2, m);
        t3_merge(t, o);
      }
      if (l15 == 0) {
        int row = wr * 64 + r * 16 + quad * 4 + reg;
        float* d = red + (row * 2 + wc) * 5;
        d[0] = t.s1; d[1] = t.s2; d[2] = t.s3; d[3] = (float)t.n1; d[4] = (float)t.n2;
      }
    }
  }
  __syncthreads();
  if (tid < 128) {
    const float* d0 = red + (tid * 2) * 5;
    const float* d1 = red + (tid * 2 + 1) * 5;
    T3 a; a.s1 = d0[0]; a.s2 = d0[1]; a.s3 = d0[2]; a.n1 = (int)d0[3]; a.n2 = (int)d0[4];
    T3 b; b.s1 = d1[0]; b.s2 = d1[1]; b.s3 = d1[2]; b.n1 = (int)d1[3]; b.n2 = (int)d1[4];
    t3_merge(a, b);
    float* p = part + ((size_t)(m0 + tid) * 4 + bn) * 5;
    p[0] = a.s1; p[1] = a.s2; p[2] = a.s3; p[3] = (float)a.n1; p[4] = (float)a.n2;
  }
}

// ---------------------------------------------------------------------------
// comb + recheckA + gather fused (R6, verified). Wave -> row.
__global__ __launch_bounds__(256) void vq_final(
    const float* __restrict__ part, const float* __restrict__ z,
    const float* __restrict__ cb, const float* __restrict__ Aws,
    const float* __restrict__ Wws, float* __restrict__ out_idx,
    float* __restrict__ out_q, int* __restrict__ wl2, int* __restrict__ cnt)
{
  const int wave = threadIdx.x >> 6, lane = threadIdx.x & 63;
  const int row = blockIdx.x * 4 + wave;
  const float* p = part + (size_t)row * 20;
  T3 a; a.s1 = p[0]; a.s2 = p[1]; a.s3 = p[2]; a.n1 = (int)p[3]; a.n2 = (int)p[4];
#pragma unroll
  for (int j = 1; j < 4; ++j) {
    const float* q = p + j * 5;
    T3 b; b.s1 = q[0]; b.s2 = q[1]; b.s3 = q[2]; b.n1 = (int)q[3]; b.n2 = (int)q[4];
    t3_merge(a, b);
  }
  unsigned int f = 0;
  if (a.s2 - a.s1 < WINDOW) f = (a.s3 - a.s1 < WINDOW) ? 2u : 1u;
  if (f == 2u) {                       // rare: full rescan handles everything
    if (lane == 0) wl2[atomicAdd(&cnt[1], 1)] = row;
    return;
  }
  int win = a.n1;
  if (f == 1u) {                       // fp64 top-2 recheck (math as before)
    int n1 = a.n1, n2 = a.n2;
    int b = row >> 10, hw = row & 1023;
    const float* zr = z + (size_t)b * IMG_STRIDE + hw;
    const float* c1p = cb + (size_t)n1 * D_DIM;
    const float* c2p = cb + (size_t)n2 * D_DIM;
    double d1 = 0.0, d2 = 0.0;
#pragma unroll
    for (int j = 0; j < 8; ++j) {
      int c = lane + 64 * j;
      double zv = (double)zr[(size_t)c * HW];
      d1 += zv * (double)c1p[c];
      d2 += zv * (double)c2p[c];
    }
#pragma unroll
    for (int off = 32; off > 0; off >>= 1) {
      d1 += __shfl_down(d1, off);
      d2 += __shfl_down(d2, off);
    }
    if (lane == 0) {
      float A_ = Aws[row];
      float e1 = fadd32(fadd32(A_, -2.f * (float)d1), Wws[n1]);
      float e2 = fadd32(fadd32(A_, -2.f * (float)d2), Wws[n2]);
      win = (e2 < e1 || (e2 == e1 && n2 < n1)) ? n2 : n1;
    }
    win = __shfl(win, 0);
  }
  if (lane == 0) out_idx[row] = (float)win;
  const float4* src = (const float4*)(cb + (size_t)win * D_DIM);
  float4* dst = (float4*)(out_q + (size_t)row * D_DIM);
  dst[lane]      = src[lane];
  dst[lane + 64] = src[lane + 64];
}

// Full 1024-code fp64 rescan for flag==2 rows (rare); writes out_q row too.
__global__ __launch_bounds__(256) void vq_recheckB(
    const float* __restrict__ z, const float* __restrict__ cb,
    const float* __restrict__ Aws, const float* __restrict__ Wws,
    const int* __restrict__ wl2, const int* __restrict__ cnt,
    float* __restrict__ out_idx, float* __restrict__ out_q)
{
  __shared__ double zd[512];
  __shared__ float rd[256];
  __shared__ int rn[256];
  const int c2 = cnt[1];
  for (int t = blockIdx.x; t < c2; t += gridDim.x) {
    int row = wl2[t];
    int b = row >> 10, hw = row & 1023;
    const float* zr = z + (size_t)b * IMG_STRIDE + hw;
    for (int c = threadIdx.x; c < 512; c += 256) zd[c] = (double)zr[(size_t)c * HW];
    __syncthreads();
    float best = 3.4e38f; int bn_ = 0;
    float A_ = Aws[row];
    for (int k = 0; k < 4; ++k) {
      int n = k * 256 + threadIdx.x;
      const float* cn = cb + (size_t)n * D_DIM;
      double a0 = 0.0, a1 = 0.0, a2 = 0.0, a3 = 0.0;
#pragma unroll 8
      for (int c4 = 0; c4 < 128; ++c4) {
        float4 w4 = *(const float4*)(cn + 4 * c4);
        a0 += zd[4 * c4 + 0] * (double)w4.x;
        a1 += zd[4 * c4 + 1] * (double)w4.y;
        a2 += zd[4 * c4 + 2] * (double)w4.z;
        a3 += zd[4 * c4 + 3] * (double)w4.w;
      }
      double dot = (a0 + a1) + (a2 + a3);
      float e = fadd32(fadd32(A_, -2.f * (float)dot), Wws[n]);
      if (e < best || (e == best && n < bn_)) { best = e; bn_ = n; }
    }
    rd[threadIdx.x] = best; rn[threadIdx.x] = bn_;
    __syncthreads();
    for (int s = 128; s > 0; s >>= 1) {
      if (threadIdx.x < s) {
        float eo = rd[threadIdx.x + s]; int no = rn[threadIdx.x + s];
        if (eo < rd[threadIdx.x] || (eo == rd[threadIdx.x] && no < rn[threadIdx.x])) {
          rd[threadIdx.x] = eo; rn[threadIdx.x] = no;
        }
      }
      __syncthreads();
    }
    int winb = rn[0];
    if (threadIdx.x == 0) out_idx[row] = (float)winb;
    {
      const float4* src = (const float4*)(cb + (size_t)winb * D_DIM);
      float4* dst = (float4*)(out_q + (size_t)row * D_DIM);
      if (threadIdx.x < 128) dst[threadIdx.x] = src[threadIdx.x];
    }
    __syncthreads();
  }
}

extern "C" void kernel_launch(void* const* d_in, const int* in_sizes, int n_in,
                              void* d_out, int out_size, void* d_ws, size_t ws_size,
                              hipStream_t stream) {
  const float* z  = (const float*)d_in[0];
  const float* cb = (const float*)d_in[1];
  float* out_q   = (float*)d_out;
  float* out_idx = (float*)d_out + (size_t)M_ROWS * D_DIM;
  char* zh_b = (char*)d_out;                // out_q region doubles as zh scratch
  char* ws = (char*)d_ws;
  char* wh_b = ws + WH_OFF;
  float* Aws = (float*)(ws + A_OFF);
  float* Wws = (float*)(ws + W_OFF);
  float* part = (float*)(ws + PART_OFF);
  int* wl2 = (int*)(ws + WL2_OFF);
  int* cnt = (int*)(ws + CNT_OFF);

  vq_prep    <<<516, 256, 0, stream>>>(z, Aws, zh_b, cb, Wws, wh_b, cnt);
  vq_score   <<<1024, 256, 0, stream>>>(zh_b, wh_b, Wws, part);
  vq_final   <<<8192, 256, 0, stream>>>(part, z, cb, Aws, Wws, out_idx, out_q, wl2, cnt);
  vq_recheckB<<<512, 256, 0, stream>>>(z, cb, Aws, Wws, wl2, cnt, out_idx, out_q);
}

// Round 10
// 301.484 us; speedup vs baseline: 1.0166x; 1.0166x over previous
//
#include <hip/hip_runtime.h>
#include <hip/hip_bf16.h>

// Problem constants
#define M_ROWS  32768   // B*H*W
#define D_DIM   512     // C == latent dim
#define K_CODES 1024
#define HW      1024
#define IMG_STRIDE (D_DIM * HW)   // 524288

// d_out scratch: zh swizzled bf16 (32 MB) lives in the out_q region until
// vq_final/vq_recheckB overwrite it (zh is dead after vq_score).
// ws layout (bytes):
#define WH_OFF   0u          // 1 MB   swizzled cb-hi bf16
#define A_OFF    1048576u    // 128 KB A[i] (numpy-pairwise)
#define W_OFF    1179648u    // 4 KB   W[n]
#define PART_OFF 1312768u    // 2.62 MB per-(row,bn) top3 partials
#define WL2_OFF  4065280u    // 128 KB worklist flag==2
#define CNT_OFF  4196352u    // 8 B    counters

// 1-term bf16 error: pairwise sigma ~4.3e-5 -> 7.5 sigma = 3.2e-4, plus fp32
// reorder/grid window 1.22e-4 -> 4.4e-4; pad to 5e-4.
#define WINDOW 5.0e-4f

// ---- exact RNE fp32 ops the compiler can't contract/reassociate ----
__device__ __forceinline__ float fmul32(float a, float b) {
  float r; asm volatile("v_mul_f32 %0, %1, %2" : "=v"(r) : "v"(a), "v"(b)); return r;
}
__device__ __forceinline__ float fadd32(float a, float b) {
  float r; asm volatile("v_add_f32 %0, %1, %2" : "=v"(r) : "v"(a), "v"(b)); return r;
}
__device__ __forceinline__ float pair8(const float* r) {
  return fadd32(fadd32(fadd32(r[0], r[1]), fadd32(r[2], r[3])),
                fadd32(fadd32(r[4], r[5]), fadd32(r[6], r[7])));
}

__device__ __forceinline__ unsigned short f2bf(float x) {
  __hip_bfloat16 h = __float2bfloat16(x);
  unsigned short u; __builtin_memcpy(&u, &h, 2); return u;
}

typedef __attribute__((ext_vector_type(8))) short b8;
typedef __attribute__((ext_vector_type(4))) float f4;

// top-3 tracking (values s1<=s2<=s3; indices for first two; first-index ties)
struct T3 { float s1, s2, s3; int n1, n2; };
__device__ __forceinline__ void t3_merge(T3& a, const T3& bb) {
  T3 x = a, y = bb;
  bool bf = (y.s1 < x.s1) || (y.s1 == x.s1 && y.n1 < x.n1);
  if (bf) { T3 t = x; x = y; y = t; }
  float rs2; int rn2; float rs3;
  bool c2 = (y.s1 < x.s2) || (y.s1 == x.s2 && y.n1 < x.n2);
  if (c2) { rs2 = y.s1; rn2 = y.n1; rs3 = fminf(x.s2, y.s2); }
  else    { rs2 = x.s2; rn2 = x.n2; rs3 = fminf(x.s3, y.s1); }
  a.s1 = x.s1; a.n1 = x.n1; a.s2 = rs2; a.n2 = rn2; a.s3 = rs3;
}

// ---------------------------------------------------------------------------
// R9: reverted to R6-exact structure (coop mega-kernel failed: cooperative
// launch incompatible with the harness graph capture -> kernel never ran).
// prep (blocks 0..255) + prepw (blocks 256..263) in one dispatch.
__global__ __launch_bounds__(128) void vq_prep(const float* __restrict__ z,
                                               float* __restrict__ A,
                                               char* __restrict__ zh_b,
                                               const float* __restrict__ cb,
                                               float* __restrict__ W,
                                               char* __restrict__ wh_b,
                                               int* __restrict__ cnt) {
  __shared__ float zs[2][64 * 68];
  if (blockIdx.x >= 256) {      // ---- prepw part (8 blocks x 128 threads) ----
    if (blockIdx.x == 256 && threadIdx.x < 2) cnt[threadIdx.x] = 0;
    const int n = (blockIdx.x - 256) * 128 + threadIdx.x;
    const float* wp = cb + (size_t)n * D_DIM;
    const size_t nbase = (size_t)(n >> 4) * 1024 + (size_t)(n & 15) * 16;
    float r8w[8], blkw[4];
    alignas(16) unsigned short hsw[8];
#pragma unroll
    for (int bb = 0; bb < 4; ++bb) {
#pragma unroll
      for (int g = 0; g < 16; ++g) {
        float vv[8];
#pragma unroll
        for (int k = 0; k < 8; ++k) vv[k] = wp[bb * 128 + g * 8 + k];
#pragma unroll
        for (int k = 0; k < 8; ++k) {
          float pq = fmul32(vv[k], vv[k]);
          if (g == 0) r8w[k] = pq;
          else        r8w[k] = fadd32(r8w[k], pq);
          hsw[k] = f2bf(vv[k]);
        }
        const int kc = bb * 4 + (g >> 2), q = g & 3;
        *(uint4*)(wh_b + (size_t)kc * 65536 + q * 256 + nbase) = *(uint4*)hsw;
      }
      blkw[bb] = pair8(r8w);
    }
    W[n] = fadd32(fadd32(blkw[0], blkw[1]), fadd32(blkw[2], blkw[3]));
    return;
  }
  // ---- prep part (256 blocks x 128 threads) ----
  const int wave = threadIdx.x >> 6, t = threadIdx.x & 63;
  const int i0 = blockIdx.x * 128 + wave * 64;
  const int b = i0 >> 10, hw0 = i0 & 1023;
  const float* zbase = z + (size_t)b * IMG_STRIDE + hw0;
  float* zsw = zs[wave];
  const int pos = i0 + t;
  const size_t mbase = (size_t)(pos >> 4) * 1024 + (size_t)(pos & 15) * 16;
  float r8[8], blk[4];
  alignas(16) unsigned short hs[8];
#pragma unroll
  for (int ch = 0; ch < 8; ++ch) {
    __syncthreads();
    {
      const int l = t & 15, j0 = t >> 4;
#pragma unroll
      for (int jj = 0; jj < 16; ++jj) {
        int j = j0 * 16 + jj;
        float4 vv = *(const float4*)(zbase + (size_t)(ch * 64 + j) * HW + 4 * l);
        *(float4*)(zsw + j * 68 + 4 * l) = vv;
      }
    }
    __syncthreads();
#pragma unroll
    for (int j = 0; j < 64; ++j) {
      const int c = ch * 64 + j;
      float v = zsw[j * 68 + t];
      hs[j & 7] = f2bf(v);
      if ((j & 7) == 7) {
        const int kc = c >> 5, q = (c >> 3) & 3;
        *(uint4*)(zh_b + (size_t)kc * 2097152 + q * 256 + mbase) = *(uint4*)hs;
      }
      float pq = fmul32(v, v);
      const int k = c & 7, m = c & 127;
      if (m < 8) r8[k] = pq;
      else       r8[k] = fadd32(r8[k], pq);
      if (m == 127) blk[c >> 7] = pair8(r8);
    }
  }
  A[pos] = fadd32(fadd32(blk[0], blk[1]), fadd32(blk[2], blk[3]));
}

// ---------------------------------------------------------------------------
// R9 score experiment: 64x256 block tile (was 128x256). The 128-tile is
// register-walled at 2 waves/SIMD (116 VGPR + 128 acc AGPR = 244); if the
// 50% idle is exposed latency, +50% occupancy should cut it. acc[4][4]
// (64 AGPR) + frags 64 VGPR -> ~168 regs -> launch_bounds(256,3) forces
// 3 waves/SIMD. Grid 2048 = bm 512 x bn 4; wave = 64-col quarter. Same
// products, same kc chain order, same ascending-n scan/merge -> bit-equal.
// If this REGRESSES, the kernel is VMEM-issue-bound (16 MFMA : 8 loads per
// kc vs 32:12 before) — revert score only next round.
__global__ __launch_bounds__(256, 3) void vq_score(
    const char* __restrict__ zh_b, const char* __restrict__ wh_b,
    const float* __restrict__ Wws, float* __restrict__ part)
{
  __shared__ float red[1280];   // [64 rows][4 w][5] epilogue reduce
  const int tid = threadIdx.x;
  const int lane = tid & 63, w = tid >> 6;    // wave = column quarter
  const int bm = blockIdx.x & 511, bn = blockIdx.x >> 9;
  const int m0 = bm * 64, n0 = bn * 256;

  f4 acc[4][4];
#pragma unroll
  for (int r = 0; r < 4; ++r)
#pragma unroll
    for (int v = 0; v < 4; ++v) acc[r][v] = (f4)(0.0f);

  // A seg r (16 rows): zh[kc*2M + (bm*4 + r)*1024 + lane*16]
  // B seg (w*4+v):     wh[kc*64K + bn*16384 + (w*4+v)*1024 + lane*16]
  const char* gA_w = zh_b + (size_t)bm * 4096 + (size_t)lane * 16;
  const char* gB_w = wh_b + (size_t)bn * 16384 + (size_t)(w * 4) * 1024 + (size_t)lane * 16;

  b8 ar[2][4], br[2][4];
#pragma unroll
  for (int r = 0; r < 4; ++r)
    ar[0][r] = *(const b8*)(gA_w + (size_t)r * 1024);
#pragma unroll
  for (int v = 0; v < 4; ++v)
    br[0][v] = *(const b8*)(gB_w + (size_t)v * 1024);

#pragma unroll
  for (int kc = 0; kc < 16; ++kc) {
    const int cur = kc & 1, nxt = cur ^ 1;
    if (kc + 1 < 16) {
      const char* gA = gA_w + (size_t)(kc + 1) * 2097152;
      const char* gB = gB_w + (size_t)(kc + 1) * 65536;
#pragma unroll
      for (int r = 0; r < 4; ++r) ar[nxt][r] = *(const b8*)(gA + (size_t)r * 1024);
#pragma unroll
      for (int v = 0; v < 4; ++v) br[nxt][v] = *(const b8*)(gB + (size_t)v * 1024);
    }
#pragma unroll
    for (int r = 0; r < 4; ++r) {
#pragma unroll
      for (int v = 0; v < 4; ++v)
        acc[r][v] = __builtin_amdgcn_mfma_f32_16x16x32_bf16(ar[cur][r], br[cur][v],
                                                            acc[r][v], 0, 0, 0);
    }
  }

  // epilogue: s = W - 2M; per-row top-3 across this block's 256 n
  const int l15 = lane & 15, quad = lane >> 4;
  float sW[4];
#pragma unroll
  for (int v = 0; v < 4; ++v) sW[v] = Wws[n0 + w * 64 + v * 16 + l15];

#pragma unroll
  for (int r = 0; r < 4; ++r) {
#pragma unroll
    for (int reg = 0; reg < 4; ++reg) {
      T3 t; t.s1 = t.s2 = t.s3 = 3.4e38f; t.n1 = 0; t.n2 = 0;
#pragma unroll
      for (int v = 0; v < 4; ++v) {           // ascending n within lane
        float s = fmaf(-2.f, acc[r][v][reg], sW[v]);
        int n = n0 + w * 64 + v * 16 + l15;
        if (s < t.s1)      { t.s3 = t.s2; t.s2 = t.s1; t.n2 = t.n1; t.s1 = s; t.n1 = n; }
        else if (s < t.s2) { t.s3 = t.s2; t.s2 = s; t.n2 = n; }
        else if (s < t.s3) { t.s3 = s; }
      }
#pragma unroll
      for (int m = 1; m <= 8; m <<= 1) {   // butterfly within 16-lane quad
        T3 o;
        o.s1 = __shfl_xor(t.s1, m); o.s2 = __shfl_xor(t.s2, m); o.s3 = __shfl_xor(t.s3, m);
        o.n1 = __shfl_xor(t.n1, m); o.n2 = __shfl_xor(t.n2, m);
        t3_merge(t, o);
      }
      if (l15 == 0) {
        int row = r * 16 + quad * 4 + reg;
        float* d = red + (row * 4 + w) * 5;
        d[0] = t.s1; d[1] = t.s2; d[2] = t.s3; d[3] = (float)t.n1; d[4] = (float)t.n2;
      }
    }
  }
  __syncthreads();
  if (tid < 64) {
    const float* d0 = red + (tid * 4) * 5;
    T3 a; a.s1 = d0[0]; a.s2 = d0[1]; a.s3 = d0[2]; a.n1 = (int)d0[3]; a.n2 = (int)d0[4];
#pragma unroll
    for (int j = 1; j < 4; ++j) {            // merge quarters ascending n
      const float* d1 = red + (tid * 4 + j) * 5;
      T3 b; b.s1 = d1[0]; b.s2 = d1[1]; b.s3 = d1[2]; b.n1 = (int)d1[3]; b.n2 = (int)d1[4];
      t3_merge(a, b);
    }
    float* p = part + ((size_t)(m0 + tid) * 4 + bn) * 5;
    p[0] = a.s1; p[1] = a.s2; p[2] = a.s3; p[3] = (float)a.n1; p[4] = (float)a.n2;
  }
}

// ---------------------------------------------------------------------------
// comb + recheckA + gather fused (R6, verified). Wave -> row.
__global__ __launch_bounds__(256) void vq_final(
    const float* __restrict__ part, const float* __restrict__ z,
    const float* __restrict__ cb, const float* __restrict__ Aws,
    const float* __restrict__ Wws, float* __restrict__ out_idx,
    float* __restrict__ out_q, int* __restrict__ wl2, int* __restrict__ cnt)
{
  const int wave = threadIdx.x >> 6, lane = threadIdx.x & 63;
  const int row = blockIdx.x * 4 + wave;
  const float* p = part + (size_t)row * 20;
  T3 a; a.s1 = p[0]; a.s2 = p[1]; a.s3 = p[2]; a.n1 = (int)p[3]; a.n2 = (int)p[4];
#pragma unroll
  for (int j = 1; j < 4; ++j) {
    const float* q = p + j * 5;
    T3 b; b.s1 = q[0]; b.s2 = q[1]; b.s3 = q[2]; b.n1 = (int)q[3]; b.n2 = (int)q[4];
    t3_merge(a, b);
  }
  unsigned int f = 0;
  if (a.s2 - a.s1 < WINDOW) f = (a.s3 - a.s1 < WINDOW) ? 2u : 1u;
  if (f == 2u) {                       // rare: full rescan handles everything
    if (lane == 0) wl2[atomicAdd(&cnt[1], 1)] = row;
    return;
  }
  int win = a.n1;
  if (f == 1u) {                       // fp64 top-2 recheck (math as before)
    int n1 = a.n1, n2 = a.n2;
    int b = row >> 10, hw = row & 1023;
    const float* zr = z + (size_t)b * IMG_STRIDE + hw;
    const float* c1p = cb + (size_t)n1 * D_DIM;
    const float* c2p = cb + (size_t)n2 * D_DIM;
    double d1 = 0.0, d2 = 0.0;
#pragma unroll
    for (int j = 0; j < 8; ++j) {
      int c = lane + 64 * j;
      double zv = (double)zr[(size_t)c * HW];
      d1 += zv * (double)c1p[c];
      d2 += zv * (double)c2p[c];
    }
#pragma unroll
    for (int off = 32; off > 0; off >>= 1) {
      d1 += __shfl_down(d1, off);
      d2 += __shfl_down(d2, off);
    }
    if (lane == 0) {
      float A_ = Aws[row];
      float e1 = fadd32(fadd32(A_, -2.f * (float)d1), Wws[n1]);
      float e2 = fadd32(fadd32(A_, -2.f * (float)d2), Wws[n2]);
      win = (e2 < e1 || (e2 == e1 && n2 < n1)) ? n2 : n1;
    }
    win = __shfl(win, 0);
  }
  if (lane == 0) out_idx[row] = (float)win;
  const float4* src = (const float4*)(cb + (size_t)win * D_DIM);
  float4* dst = (float4*)(out_q + (size_t)row * D_DIM);
  dst[lane]      = src[lane];
  dst[lane + 64] = src[lane + 64];
}

// Full 1024-code fp64 rescan for flag==2 rows (rare); writes out_q row too.
__global__ __launch_bounds__(256) void vq_recheckB(
    const float* __restrict__ z, const float* __restrict__ cb,
    const float* __restrict__ Aws, const float* __restrict__ Wws,
    const int* __restrict__ wl2, const int* __restrict__ cnt,
    float* __restrict__ out_idx, float* __restrict__ out_q)
{
  __shared__ double zd[512];
  __shared__ float rd[256];
  __shared__ int rn[256];
  const int c2 = cnt[1];
  for (int t = blockIdx.x; t < c2; t += gridDim.x) {
    int row = wl2[t];
    int b = row >> 10, hw = row & 1023;
    const float* zr = z + (size_t)b * IMG_STRIDE + hw;
    for (int c = threadIdx.x; c < 512; c += 256) zd[c] = (double)zr[(size_t)c * HW];
    __syncthreads();
    float best = 3.4e38f; int bn_ = 0;
    float A_ = Aws[row];
    for (int k = 0; k < 4; ++k) {
      int n = k * 256 + threadIdx.x;
      const float* cn = cb + (size_t)n * D_DIM;
      double a0 = 0.0, a1 = 0.0, a2 = 0.0, a3 = 0.0;
#pragma unroll 8
      for (int c4 = 0; c4 < 128; ++c4) {
        float4 w4 = *(const float4*)(cn + 4 * c4);
        a0 += zd[4 * c4 + 0] * (double)w4.x;
        a1 += zd[4 * c4 + 1] * (double)w4.y;
        a2 += zd[4 * c4 + 2] * (double)w4.z;
        a3 += zd[4 * c4 + 3] * (double)w4.w;
      }
      double dot = (a0 + a1) + (a2 + a3);
      float e = fadd32(fadd32(A_, -2.f * (float)dot), Wws[n]);
      if (e < best || (e == best && n < bn_)) { best = e; bn_ = n; }
    }
    rd[threadIdx.x] = best; rn[threadIdx.x] = bn_;
    __syncthreads();
    for (int s = 128; s > 0; s >>= 1) {
      if (threadIdx.x < s) {
        float eo = rd[threadIdx.x + s]; int no = rn[threadIdx.x + s];
        if (eo < rd[threadIdx.x] || (eo == rd[threadIdx.x] && no < rn[threadIdx.x])) {
          rd[threadIdx.x] = eo; rn[threadIdx.x] = no;
        }
      }
      __syncthreads();
    }
    int winb = rn[0];
    if (threadIdx.x == 0) out_idx[row] = (float)winb;
    {
      const float4* src = (const float4*)(cb + (size_t)winb * D_DIM);
      float4* dst = (float4*)(out_q + (size_t)row * D_DIM);
      if (threadIdx.x < 128) dst[threadIdx.x] = src[threadIdx.x];
    }
    __syncthreads();
  }
}

extern "C" void kernel_launch(void* const* d_in, const int* in_sizes, int n_in,
                              void* d_out, int out_size, void* d_ws, size_t ws_size,
                              hipStream_t stream) {
  const float* z  = (const float*)d_in[0];
  const float* cb = (const float*)d_in[1];
  float* out_q   = (float*)d_out;
  float* out_idx = (float*)d_out + (size_t)M_ROWS * D_DIM;
  char* zh_b = (char*)d_out;                // out_q region doubles as zh scratch
  char* ws = (char*)d_ws;
  char* wh_b = ws + WH_OFF;
  float* Aws = (float*)(ws + A_OFF);
  float* Wws = (float*)(ws + W_OFF);
  float* part = (float*)(ws + PART_OFF);
  int* wl2 = (int*)(ws + WL2_OFF);
  int* cnt = (int*)(ws + CNT_OFF);

  vq_prep    <<<264, 128, 0, stream>>>(z, Aws, zh_b, cb, Wws, wh_b, cnt);
  vq_score   <<<2048, 256, 0, stream>>>(zh_b, wh_b, Wws, part);
  vq_final   <<<8192, 256, 0, stream>>>(part, z, cb, Aws, Wws, out_idx, out_q, wl2, cnt);
  vq_recheckB<<<512, 256, 0, stream>>>(z, cb, Aws, Wws, wl2, cnt, out_idx, out_q);
}